// Round 9
// baseline (148.563 us; speedup 1.0000x reference)
//
#include <hip/hip_runtime.h>

// DGI forward on MI355X — R9: R6 backbone; split-K=2; parallel k1; R6 tail.
// K1 (256 blocks: comm map, S zero; F = f16[seq@W] tile-transposed) ;
// K2 (Pp = adj@F split-K=2 partials, BM=64, XCD-pinned 2MB F-slices,
//     NT adj loads / NT Pp stores, reg-staged 1KB-contiguous A) ;
// K2R (h = relu(sum2(Pp)/2^12 + b), 2048 blocks) ; K3a (community sums S) ;
// K3b (c=sigmoid(S/1024), cw=c@Wb^T) ; K5 (per-node bilinear score -> out).

#define NN    8192
#define NCOLS 256
#define ASCALE 4096.0f
#define AINV  (1.0f/4096.0f)

typedef _Float16 half8 __attribute__((ext_vector_type(8)));
typedef _Float16 half4v __attribute__((ext_vector_type(4)));
typedef float    f32x4 __attribute__((ext_vector_type(4)));

__device__ __forceinline__ void gload16(const void* g, void* l) {
  __builtin_amdgcn_global_load_lds(
      (const __attribute__((address_space(1))) char*)g,
      (__attribute__((address_space(3))) char*)l, 16, 0, 0);
}

// ---------------- K1: F tiles = f16(seq@W) [tile32][col256][k32]; comm map ----------------
// 256 blocks: blk>>7 selects seq, blk&127 selects 64-row tile.
__global__ __launch_bounds__(256) void k1_fts(const float* __restrict__ seq1,
                                              const float* __restrict__ seq2,
                                              const float* __restrict__ W,
                                              _Float16* __restrict__ F,
                                              const int* __restrict__ cc,
                                              int* __restrict__ node_comm,
                                              float* __restrict__ S) {
  __shared__ char lds[65536];
  _Float16* Wt  = (_Float16*)lds;             // 32KB: W^T f16, swizzled [128 col][128 d]
  float*    sSeq = (float*)(lds + 32768);     // 32KB: seq tile f32 swizzled; reused as out image
  const int tid = threadIdx.x;
  const int lane = tid & 63;
  const int w = tid >> 6;                     // 4 waves
  const int l15 = lane & 15;
  const int g = lane >> 4;
  const int s = blockIdx.x >> 7;              // 0: seq1, 1: seq2
  const int mt = blockIdx.x & 127;
  const int m0 = mt * 64;

  if (s == 0 && tid < 64) {                   // comm map: 128 blocks x 64 = 8192
    int i = mt * 64 + tid;
    node_comm[cc[i]] = i >> 10;               // CS = 1024
  }
  if (blockIdx.x == 0) {                      // zero S for K3a atomics
    for (int j = tid; j < 1024; j += 256) S[j] = 0.0f;
  }

  {                                           // W^T f16 swizzled, vectorized build
    const float4* W4g = (const float4*)W;     // W row-major [d][h], 4096 float4s
#pragma unroll
    for (int i = 0; i < 16; ++i) {
      int idx4 = i * 256 + tid;
      float4 wv = W4g[idx4];
      int d = idx4 >> 5;                      // 32 float4 per d-row
      int hc = (idx4 & 31) * 4;
#pragma unroll
      for (int j = 0; j < 4; ++j) {
        int byte = ((hc + j) * 256 + d * 2) ^ (((hc + j) & 7) << 4);
        *(_Float16*)(lds + byte) = (_Float16)(((const float*)&wv)[j]);
      }
    }
  }

  const float* sp = s ? seq2 : seq1;
  const int srow = tid >> 5;                  // 0..7
  const int sck = tid & 31;                   // 16B chunk in 512B row
  __syncthreads();                            // Wt built
#pragma unroll
  for (int i = 0; i < 8; ++i) {               // stage 64x128 f32, swizzled src
    int row = i * 8 + srow;
    gload16(sp + (size_t)(m0 + row) * 128 + ((sck ^ (row & 7)) << 2),
            (char*)sSeq + i * 4096 + w * 1024);
  }
  asm volatile("s_waitcnt vmcnt(0)" ::: "memory");
  __syncthreads();

  f32x4 acc[4][2] = {};
  const float4* S4 = (const float4*)sSeq;
  const float4* W4 = (const float4*)Wt;
#pragma unroll
  for (int kk = 0; kk < 4; ++kk) {
    half8 bf[2];
#pragma unroll
    for (int nf = 0; nf < 2; ++nf) {
      int col = w * 32 + nf * 16 + l15;
      float4 bv = W4[(col * 16 + kk * 4 + g) ^ (col & 7)];
      bf[nf] = *(const half8*)&bv;
    }
#pragma unroll
    for (int mf = 0; mf < 4; ++mf) {
      int row = mf * 16 + l15;
      int bidx = row * 32 + kk * 8 + g * 2;
      float4 u = S4[bidx ^ (row & 7)];
      float4 v = S4[(bidx + 1) ^ (row & 7)];
      half8 af;
#pragma unroll
      for (int j = 0; j < 4; ++j) af[j] = (_Float16)(((const float*)&u)[j]);
#pragma unroll
      for (int j = 0; j < 4; ++j) af[4 + j] = (_Float16)(((const float*)&v)[j]);
#pragma unroll
      for (int nf = 0; nf < 2; ++nf)
        acc[mf][nf] = __builtin_amdgcn_mfma_f32_16x16x32_f16(af, bf[nf], acc[mf][nf], 0, 0, 0);
    }
  }
  __syncthreads();
  _Float16* img = (_Float16*)sSeq;            // emit image [kt][c][k]
#pragma unroll
  for (int mf = 0; mf < 4; ++mf)
#pragma unroll
    for (int nf = 0; nf < 2; ++nf) {
      int col = w * 32 + nf * 16 + l15;
#pragma unroll
      for (int j = 0; j < 4; ++j) {
        int kl = mf * 16 + g * 4 + j;         // local node (C/D: row=(l>>4)*4+j)
        img[(kl >> 5) * 4096 + col * 32 + (kl & 31)] = (_Float16)acc[mf][nf][j];
      }
    }
  __syncthreads();
  const float4* src4 = (const float4*)sSeq;
#pragma unroll
  for (int i = 0; i < 4; ++i) {               // 16KB -> global, linear
    int e = i * 256 + tid;
    int kt = e >> 9, off = e & 511;
    ((float4*)(F + (size_t)(2 * mt + kt) * 8192))[s * 512 + off] = src4[e];
  }
}

// ---------------- K2: split-K=2 GEMM partials Pp[ks][m][n] = (adj*2^12)@F ----------------
// 256 blocks x 512. BM=64, K=4096/ks. ks = xcd>>2 -> 2MB F-slice per XCD L2.
// adj NT 1KB-contiguous reg-staged -> f16 LDS [2][64][256]; B direct from L2.
__global__ __launch_bounds__(512) void k2_gemm(const float* __restrict__ adj,
                                               const _Float16* __restrict__ F,
                                               float* __restrict__ Pp) {
  __shared__ __align__(16) _Float16 sA[2][16384];  // [buf][row64][k256], swz ((row&15)<<4)
  const int tid = threadIdx.x;                // 512
  const int lane = tid & 63;
  const int w = tid >> 6;                     // 8 waves
  const int l15 = lane & 15;
  const int g = lane >> 4;
  const int id = blockIdx.x;
  const int xcd = id & 7;                     // dispatch round-robin -> XCD
  const int ks = xcd >> 2;                    // 0..1: F-slice pinned to XCD quad
  const int mtile = (id >> 3) * 4 + (xcd & 3);     // 0..127, bijective
  const int row0 = mtile * 64;
  const int wm = w >> 2, wn = w & 3;          // 2x4 wave grid, 32x64 per wave

  const float* abase = adj + (size_t)(row0 + w * 8) * NN + (size_t)ks * 4096 + lane * 4;
  const _Float16* fbase = F + (size_t)(ks * 128) * 8192;

  f32x4 acc[2][4] = {};

  auto cvt_store = [&](int b, int i, f32x4 v) {   // row w*8+i of buf b
    int row = w * 8 + i;
    char* dst = (char*)sA[b] + row * 512 + ((lane * 8) ^ ((row & 15) << 4));
    half4v h;
    h[0] = (_Float16)(v[0] * ASCALE); h[1] = (_Float16)(v[1] * ASCALE);
    h[2] = (_Float16)(v[2] * ASCALE); h[3] = (_Float16)(v[3] * ASCALE);
    *(half4v*)dst = h;
  };

  {                                           // prologue: macro 0 -> buf 0 (nt)
    f32x4 pv[8];
#pragma unroll
    for (int i = 0; i < 8; ++i)
      pv[i] = __builtin_nontemporal_load((const f32x4*)(abase + (size_t)i * NN));
#pragma unroll
    for (int i = 0; i < 8; ++i) cvt_store(0, i, pv[i]);
  }
  __syncthreads();

  int colb[4], rowb[2], rsw[2];
#pragma unroll
  for (int nf = 0; nf < 4; ++nf) colb[nf] = (wn * 64 + nf * 16 + l15) * 32 + g * 8;
#pragma unroll
  for (int mf = 0; mf < 2; ++mf) {
    int row = wm * 32 + mf * 16 + l15;
    rowb[mf] = row * 512; rsw[mf] = (row & 15) << 4;
  }

  half8 bfc[4], bfn[4];
#pragma unroll
  for (int nf = 0; nf < 4; ++nf) {            // preload bf for (m=0,s=0)
    float4 t = *(const float4*)(fbase + colb[nf]);
    bfc[nf] = *(const half8*)&t;
  }

  for (int m = 0; m < 16; ++m) {              // 16 macros x BK=256
    const int b = m & 1;
    const bool lastm = (m == 15);
    const char* ab = (const char*)sA[b];
    const float* anext = abase + (m + 1) * 256;
    f32x4 ba[8];
#pragma unroll
    for (int s = 0; s < 8; ++s) {
      if (!(lastm && s == 7)) {               // bf prefetch: next sub
        const _Float16* fb = fbase + (size_t)(m * 8 + s + 1) * 8192;
#pragma unroll
        for (int nf = 0; nf < 4; ++nf) {
          float4 t = *(const float4*)(fb + colb[nf]);
          bfn[nf] = *(const half8*)&t;
        }
      }
      if (!lastm)                             // A-stage: 1 row/sub for macro m+1 (nt)
        ba[s] = __builtin_nontemporal_load((const f32x4*)(anext + (size_t)s * NN));
#pragma unroll
      for (int mf = 0; mf < 2; ++mf) {        // compute sub s (k = m*256+s*32)
        half8 af = *(const half8*)(ab + rowb[mf] + ((s * 64 + g * 16) ^ rsw[mf]));
#pragma unroll
        for (int nf = 0; nf < 4; ++nf)
          acc[mf][nf] = __builtin_amdgcn_mfma_f32_16x16x32_f16(af, bfc[nf], acc[mf][nf], 0, 0, 0);
      }
      if (!lastm && s >= 2)                   // drain row s-2 into buf b^1
        cvt_store(b ^ 1, s - 2, ba[s - 2]);
#pragma unroll
      for (int nf = 0; nf < 4; ++nf) bfc[nf] = bfn[nf];
    }
    if (!lastm) {                             // drain rows 6,7
      cvt_store(b ^ 1, 6, ba[6]); cvt_store(b ^ 1, 7, ba[7]);
    }
    __syncthreads();
  }

#pragma unroll
  for (int mf = 0; mf < 2; ++mf)
#pragma unroll
    for (int nf = 0; nf < 4; ++nf) {
      int col = wn * 64 + nf * 16 + l15;
#pragma unroll
      for (int j = 0; j < 4; ++j) {
        int row = row0 + wm * 32 + mf * 16 + g * 4 + j;
        __builtin_nontemporal_store(acc[mf][nf][j],
            Pp + ((size_t)ks * NN + row) * NCOLS + col);
      }
    }
}

// ---------------- K2R: h = relu(sum2(Pp)/2^12 + b) ----------------
__global__ void k2r_reduce(const float* __restrict__ Pp, const float* __restrict__ b,
                           float* __restrict__ h) {
  int gid = blockIdx.x * 256 + threadIdx.x;   // 0..524287 float4s
  size_t base = (size_t)gid * 4;
  f32x4 p0 = __builtin_nontemporal_load((const f32x4*)(Pp + base));
  f32x4 p1 = __builtin_nontemporal_load((const f32x4*)(Pp + base + 2097152));
  int n0 = (int)(base & 255) & 127;
  float4 r;
  r.x = fmaxf((p0[0] + p1[0]) * AINV + b[n0],     0.f);
  r.y = fmaxf((p0[1] + p1[1]) * AINV + b[n0 + 1], 0.f);
  r.z = fmaxf((p0[2] + p1[2]) * AINV + b[n0 + 2], 0.f);
  r.w = fmaxf((p0[3] + p1[3]) * AINV + b[n0 + 3], 0.f);
  *(float4*)(h + base) = r;
}

// ---------------- K3a: community sums of h1 ----------------
__global__ __launch_bounds__(128) void k3a_csum(const float* __restrict__ h,
                                                const int* __restrict__ node_comm,
                                                float* __restrict__ S) {
  int hh = threadIdx.x;
  int n0 = blockIdx.x * 32;
  float a0=0,a1=0,a2=0,a3=0,a4=0,a5=0,a6=0,a7=0;
  for (int i = 0; i < 32; ++i) {
    int node = n0 + i;
    int c = node_comm[node];
    float v = h[(size_t)node * 256 + hh];
    a0 += (c == 0) ? v : 0.f;  a1 += (c == 1) ? v : 0.f;
    a2 += (c == 2) ? v : 0.f;  a3 += (c == 3) ? v : 0.f;
    a4 += (c == 4) ? v : 0.f;  a5 += (c == 5) ? v : 0.f;
    a6 += (c == 6) ? v : 0.f;  a7 += (c == 7) ? v : 0.f;
  }
  if (a0 != 0.f) atomicAdd(&S[0 * 128 + hh], a0);
  if (a1 != 0.f) atomicAdd(&S[1 * 128 + hh], a1);
  if (a2 != 0.f) atomicAdd(&S[2 * 128 + hh], a2);
  if (a3 != 0.f) atomicAdd(&S[3 * 128 + hh], a3);
  if (a4 != 0.f) atomicAdd(&S[4 * 128 + hh], a4);
  if (a5 != 0.f) atomicAdd(&S[5 * 128 + hh], a5);
  if (a6 != 0.f) atomicAdd(&S[6 * 128 + hh], a6);
  if (a7 != 0.f) atomicAdd(&S[7 * 128 + hh], a7);
}

// ---------------- K3b: c = sigmoid(S/1024); cw = c @ Wb^T ----------------
__global__ __launch_bounds__(128) void k3b_cw(const float* __restrict__ S,
                                              const float* __restrict__ Wb,
                                              float* __restrict__ cw) {
  __shared__ float sc[128];
  int ci = blockIdx.x;                        // 0..7
  int hh = threadIdx.x;
  float m = S[ci * 128 + hh] * (1.0f / 1024.0f);
  sc[hh] = 1.0f / (1.0f + __expf(-m));
  __syncthreads();
  const float4* wr = (const float4*)(Wb + (size_t)hh * 128);
  float acc = 0.f;
#pragma unroll 8
  for (int k4 = 0; k4 < 32; ++k4) {
    float4 wv = wr[k4];
    acc += wv.x * sc[k4 * 4 + 0] + wv.y * sc[k4 * 4 + 1]
         + wv.z * sc[k4 * 4 + 2] + wv.w * sc[k4 * 4 + 3];
  }
  cw[ci * 128 + hh] = acc;
}

// ---------------- K5: per-node bilinear scores -> out ----------------
__global__ __launch_bounds__(256) void k5_score(const float* __restrict__ h,
                                                const int* __restrict__ node_comm,
                                                const float* __restrict__ cw,
                                                const float* __restrict__ bbp,
                                                float* __restrict__ out) {
  int tid = threadIdx.x;
  int q = tid & 15, nl = tid >> 4;
  int node = blockIdx.x * 16 + nl;
  int c = node_comm[node];
  const float* hr = h + (size_t)node * 256;
  const float* cr = cw + c * 128;
  float4 c0 = *(const float4*)(cr + q * 8);
  float4 c1 = *(const float4*)(cr + q * 8 + 4);
  float4 a0 = *(const float4*)(hr + q * 8);
  float4 a1 = *(const float4*)(hr + q * 8 + 4);
  float p1 = a0.x*c0.x + a0.y*c0.y + a0.z*c0.z + a0.w*c0.w
           + a1.x*c1.x + a1.y*c1.y + a1.z*c1.z + a1.w*c1.w;
  float4 b0 = *(const float4*)(hr + 128 + q * 8);
  float4 b1 = *(const float4*)(hr + 128 + q * 8 + 4);
  float p2 = b0.x*c0.x + b0.y*c0.y + b0.z*c0.z + b0.w*c0.w
           + b1.x*c1.x + b1.y*c1.y + b1.z*c1.z + b1.w*c1.w;
#pragma unroll
  for (int m = 8; m >= 1; m >>= 1) {
    p1 += __shfl_xor(p1, m, 64);
    p2 += __shfl_xor(p2, m, 64);
  }
  if (q == 0) {
    float bb = bbp[0];
    out[node] = p1 + bb;
    out[8192 + node] = p2 + bb;
  }
}

extern "C" void kernel_launch(void* const* d_in, const int* in_sizes, int n_in,
                              void* d_out, int out_size, void* d_ws, size_t ws_size,
                              hipStream_t stream) {
  (void)in_sizes; (void)n_in; (void)out_size; (void)ws_size;
  const float* seq1 = (const float*)d_in[0];
  const float* seq2 = (const float*)d_in[1];
  const float* adj  = (const float*)d_in[2];
  const int*   cc   = (const int*)d_in[3];
  const float* W    = (const float*)d_in[4];
  const float* b    = (const float*)d_in[5];
  const float* Wb   = (const float*)d_in[6];
  const float* bb   = (const float*)d_in[7];
  float* out = (float*)d_out;

  char* ws = (char*)d_ws;
  _Float16* F    = (_Float16*)(ws);                        // 4 MB
  float* h       = (float*)(ws + (4u << 20));              // 8 MB
  float* Pp      = (float*)(ws + (12u << 20));             // 16 MB
  float* S       = (float*)(ws + (44u << 20));             // 4 KB
  float* cw      = (float*)(ws + (44u << 20) + 4096);     // 4 KB
  int* node_comm = (int*)(ws + (44u << 20) + 8192);        // 32 KB

  k1_fts<<<dim3(256), dim3(256), 0, stream>>>(seq1, seq2, W, F, cc, node_comm, S);
  k2_gemm<<<dim3(256), dim3(512), 0, stream>>>(adj, F, Pp);
  k2r_reduce<<<dim3(2048), dim3(256), 0, stream>>>(Pp, b, h);
  k3a_csum<<<dim3(256), dim3(128), 0, stream>>>(h, node_comm, S);
  k3b_cw<<<dim3(8), dim3(128), 0, stream>>>(S, Wb, cw);
  k5_score<<<dim3(512), dim3(256), 0, stream>>>(h, node_comm, cw, bb, out);
}

// Round 10
// 107.172 us; speedup vs baseline: 1.3862x; 1.3862x over previous
//
#include <hip/hip_runtime.h>

// DGI forward on MI355X — R10: R6 exact backbone; Pp stored as f16 (only change).
// K1 (K0 fused: comm map, S zero; F = f16[seq@W] tile-transposed, serial 2-pass) ;
// K2 (Pp16 = adj@F split-K=4 partials, XCD-pinned 1MB F-slices, NT adj loads,
//     f16 NT Pp stores — loop byte-identical to R6) ;
// K2R (h = relu(sum4(Pp16)/2^12 + b), 2048 blocks) ; K3a (community sums S) ;
// K3b (c=sigmoid(S/1024), cw=c@Wb^T) ; K5 (per-node bilinear score -> out).

#define NN    8192
#define NCOLS 256
#define ASCALE 4096.0f
#define AINV  (1.0f/4096.0f)

typedef _Float16 half8 __attribute__((ext_vector_type(8)));
typedef _Float16 half4v __attribute__((ext_vector_type(4)));
typedef float    f32x4 __attribute__((ext_vector_type(4)));

__device__ __forceinline__ void gload16(const void* g, void* l) {
  __builtin_amdgcn_global_load_lds(
      (const __attribute__((address_space(1))) char*)g,
      (__attribute__((address_space(3))) char*)l, 16, 0, 0);
}

// ---------------- K1: F tiles = f16(seq@W) [tile32][col256][k32]; K0 fused ----------------
__global__ __launch_bounds__(256) void k1_fts(const float* __restrict__ seq1,
                                              const float* __restrict__ seq2,
                                              const float* __restrict__ W,
                                              _Float16* __restrict__ F,
                                              const int* __restrict__ cc,
                                              int* __restrict__ node_comm,
                                              float* __restrict__ S) {
  __shared__ char lds[65536];
  _Float16* Wt  = (_Float16*)lds;             // 32KB: W^T f16, swizzled [128 col][128 d]
  float*    sSeq = (float*)(lds + 32768);     // 32KB: seq tile f32 swizzled; reused as out image
  const int tid = threadIdx.x;
  const int lane = tid & 63;
  const int w = tid >> 6;                     // 4 waves
  const int l15 = lane & 15;
  const int g = lane >> 4;
  const int m0 = blockIdx.x * 64;

  if (tid < 64) {                             // K0 fold: 128 blocks x 64 = 8192
    int i = blockIdx.x * 64 + tid;
    node_comm[cc[i]] = i >> 10;               // CS = 1024
  }
  if (blockIdx.x == 0) {                      // zero S for K3a atomics
    for (int j = tid; j < 1024; j += 256) S[j] = 0.0f;
  }

  for (int it = 0; it < 64; ++it) {
    int idx = it * 256 + tid;                 // W row-major [d][h]
    int d = idx >> 7, hc = idx & 127;
    int byte = (hc * 256 + d * 2) ^ ((hc & 7) << 4);
    *(_Float16*)(lds + byte) = (_Float16)W[idx];
  }

  const float* seqp[2] = {seq1, seq2};
  const int srow = tid >> 5;                  // 0..7
  const int sck = tid & 31;                   // 16B chunk in 512B row

  for (int s = 0; s < 2; ++s) {
    __syncthreads();
    const float* sp = seqp[s];
#pragma unroll
    for (int i = 0; i < 8; ++i) {             // stage 64x128 f32, swizzled src
      int row = i * 8 + srow;
      gload16(sp + (size_t)(m0 + row) * 128 + ((sck ^ (row & 7)) << 2),
              (char*)sSeq + i * 4096 + w * 1024);
    }
    asm volatile("s_waitcnt vmcnt(0)" ::: "memory");
    __syncthreads();

    f32x4 acc[4][2] = {};
    const float4* S4 = (const float4*)sSeq;
    const float4* W4 = (const float4*)Wt;
#pragma unroll
    for (int kk = 0; kk < 4; ++kk) {
      half8 bf[2];
#pragma unroll
      for (int nf = 0; nf < 2; ++nf) {
        int col = w * 32 + nf * 16 + l15;
        float4 bv = W4[(col * 16 + kk * 4 + g) ^ (col & 7)];
        bf[nf] = *(const half8*)&bv;
      }
#pragma unroll
      for (int mf = 0; mf < 4; ++mf) {
        int row = mf * 16 + l15;
        int bidx = row * 32 + kk * 8 + g * 2;
        float4 u = S4[bidx ^ (row & 7)];
        float4 v = S4[(bidx + 1) ^ (row & 7)];
        half8 af;
#pragma unroll
        for (int j = 0; j < 4; ++j) af[j] = (_Float16)(((const float*)&u)[j]);
#pragma unroll
        for (int j = 0; j < 4; ++j) af[4 + j] = (_Float16)(((const float*)&v)[j]);
#pragma unroll
        for (int nf = 0; nf < 2; ++nf)
          acc[mf][nf] = __builtin_amdgcn_mfma_f32_16x16x32_f16(af, bf[nf], acc[mf][nf], 0, 0, 0);
      }
    }
    __syncthreads();
    _Float16* img = (_Float16*)sSeq;          // emit image [kt][c][k]
#pragma unroll
    for (int mf = 0; mf < 4; ++mf)
#pragma unroll
      for (int nf = 0; nf < 2; ++nf) {
        int col = w * 32 + nf * 16 + l15;
#pragma unroll
        for (int j = 0; j < 4; ++j) {
          int kl = mf * 16 + g * 4 + j;       // local node (C/D: row=(l>>4)*4+j)
          img[(kl >> 5) * 4096 + col * 32 + (kl & 31)] = (_Float16)acc[mf][nf][j];
        }
      }
    __syncthreads();
    const float4* src4 = (const float4*)sSeq;
#pragma unroll
    for (int i = 0; i < 4; ++i) {             // 16KB -> global, linear
      int e = i * 256 + tid;
      int kt = e >> 9, off = e & 511;
      ((float4*)(F + (size_t)(2 * blockIdx.x + kt) * 8192))[s * 512 + off] = src4[e];
    }
  }
}

// ---------------- K2: split-K GEMM partials Pp16[ks][m][n] = (adj*2^12)@F ----------------
// Loop identical to R6; ONLY the epilogue dtype changed (f32 -> f16 NT stores).
__global__ __launch_bounds__(512) void k2_gemm(const float* __restrict__ adj,
                                               const _Float16* __restrict__ F,
                                               _Float16* __restrict__ Pp) {
  __shared__ __align__(16) _Float16 sA[2][32768];  // [buf][row128][k256], swz ((row&15)<<4)
  const int tid = threadIdx.x;                // 512
  const int lane = tid & 63;
  const int w = tid >> 6;                     // 8 waves
  const int l15 = lane & 15;
  const int g = lane >> 4;
  const int id = blockIdx.x;
  const int xcd = id & 7;                     // dispatch round-robin -> XCD
  const int ks = xcd >> 1;                    // F-slice pinned to XCD pair
  const int mtile = (id >> 3) * 2 + (xcd & 1);
  const int row0 = mtile * 128;
  const int wm = w >> 2, wn = w & 3;          // 2x4 wave grid, 64x64 per wave

  const float* abase = adj + (size_t)(row0 + w * 16) * NN + (size_t)ks * 2048 + lane * 4;
  const _Float16* fbase = F + (size_t)(ks * 64) * 8192;

  f32x4 acc[4][4] = {};

  auto cvt_store = [&](int b, int i, f32x4 v) {   // row w*16+i of buf b
    int row = w * 16 + i;
    char* dst = (char*)sA[b] + row * 512 + ((lane * 8) ^ ((row & 15) << 4));
    half4v h;
    h[0] = (_Float16)(v[0] * ASCALE); h[1] = (_Float16)(v[1] * ASCALE);
    h[2] = (_Float16)(v[2] * ASCALE); h[3] = (_Float16)(v[3] * ASCALE);
    *(half4v*)dst = h;
  };

  {                                           // prologue: macro 0 -> buf 0 (nt)
    f32x4 pv[16];
#pragma unroll
    for (int i = 0; i < 16; ++i)
      pv[i] = __builtin_nontemporal_load((const f32x4*)(abase + (size_t)i * NN));
#pragma unroll
    for (int i = 0; i < 16; ++i) cvt_store(0, i, pv[i]);
  }
  __syncthreads();

  int colb[4], rowb[4], rsw[4];
#pragma unroll
  for (int nf = 0; nf < 4; ++nf) colb[nf] = (wn * 64 + nf * 16 + l15) * 32 + g * 8;
#pragma unroll
  for (int mf = 0; mf < 4; ++mf) {
    int row = wm * 64 + mf * 16 + l15;
    rowb[mf] = row * 512; rsw[mf] = (row & 15) << 4;
  }

  half8 bfc[4], bfn[4];
#pragma unroll
  for (int nf = 0; nf < 4; ++nf) {            // preload bf for (m=0,s=0)
    float4 t = *(const float4*)(fbase + colb[nf]);
    bfc[nf] = *(const half8*)&t;
  }

  for (int m = 0; m < 8; ++m) {
    const int b = m & 1;
    const bool lastm = (m == 7);
    const char* ab = (const char*)sA[b];
    const float* anext = abase + (m + 1) * 256;
    f32x4 ba[8][2];
#pragma unroll
    for (int s = 0; s < 8; ++s) {
      if (!(lastm && s == 7)) {               // bf prefetch: next sub
        const _Float16* fb = fbase + (size_t)(m * 8 + s + 1) * 8192;
#pragma unroll
        for (int nf = 0; nf < 4; ++nf) {
          float4 t = *(const float4*)(fb + colb[nf]);
          bfn[nf] = *(const half8*)&t;
        }
      }
      if (!lastm) {                           // A-stage loads for macro m+1 (nt)
        ba[s][0] = __builtin_nontemporal_load((const f32x4*)(anext + (size_t)(2 * s) * NN));
        ba[s][1] = __builtin_nontemporal_load((const f32x4*)(anext + (size_t)(2 * s + 1) * NN));
      }
#pragma unroll
      for (int mf = 0; mf < 4; ++mf) {        // compute sub s (k = m*256+s*32)
        half8 af = *(const half8*)(ab + rowb[mf] + ((s * 64 + g * 16) ^ rsw[mf]));
#pragma unroll
        for (int nf = 0; nf < 4; ++nf)
          acc[mf][nf] = __builtin_amdgcn_mfma_f32_16x16x32_f16(af, bfc[nf], acc[mf][nf], 0, 0, 0);
      }
      if (!lastm && s >= 2) {                 // drain A batch s-2 into buf b^1
        cvt_store(b ^ 1, 2 * (s - 2),     ba[s - 2][0]);
        cvt_store(b ^ 1, 2 * (s - 2) + 1, ba[s - 2][1]);
      }
#pragma unroll
      for (int nf = 0; nf < 4; ++nf) bfc[nf] = bfn[nf];
    }
    if (!lastm) {                             // drain batches 6,7
      cvt_store(b ^ 1, 12, ba[6][0]); cvt_store(b ^ 1, 13, ba[6][1]);
      cvt_store(b ^ 1, 14, ba[7][0]); cvt_store(b ^ 1, 15, ba[7][1]);
    }
    __syncthreads();
  }

#pragma unroll
  for (int mf = 0; mf < 4; ++mf)
#pragma unroll
    for (int nf = 0; nf < 4; ++nf) {
      int col = wn * 64 + nf * 16 + l15;
#pragma unroll
      for (int j = 0; j < 4; ++j) {
        int row = row0 + wm * 64 + mf * 16 + g * 4 + j;
        __builtin_nontemporal_store((_Float16)acc[mf][nf][j],
            Pp + ((size_t)ks * NN + row) * NCOLS + col);
      }
    }
}

// ---------------- K2R: h = relu(sum4(Pp16)/2^12 + b) ----------------
__global__ void k2r_reduce(const _Float16* __restrict__ Pp, const float* __restrict__ b,
                           float* __restrict__ h) {
  int gid = blockIdx.x * 256 + threadIdx.x;   // 0..524287 float4s
  size_t base = (size_t)gid * 4;
  half4v p0 = __builtin_nontemporal_load((const half4v*)(Pp + base));
  half4v p1 = __builtin_nontemporal_load((const half4v*)(Pp + base + 2097152));
  half4v p2 = __builtin_nontemporal_load((const half4v*)(Pp + base + 4194304));
  half4v p3 = __builtin_nontemporal_load((const half4v*)(Pp + base + 6291456));
  int n0 = (int)(base & 255) & 127;
  float4 r;
  r.x = fmaxf(((float)p0[0] + (float)p1[0] + (float)p2[0] + (float)p3[0]) * AINV + b[n0],     0.f);
  r.y = fmaxf(((float)p0[1] + (float)p1[1] + (float)p2[1] + (float)p3[1]) * AINV + b[n0 + 1], 0.f);
  r.z = fmaxf(((float)p0[2] + (float)p1[2] + (float)p2[2] + (float)p3[2]) * AINV + b[n0 + 2], 0.f);
  r.w = fmaxf(((float)p0[3] + (float)p1[3] + (float)p2[3] + (float)p3[3]) * AINV + b[n0 + 3], 0.f);
  *(float4*)(h + base) = r;
}

// ---------------- K3a: community sums of h1 ----------------
__global__ __launch_bounds__(128) void k3a_csum(const float* __restrict__ h,
                                                const int* __restrict__ node_comm,
                                                float* __restrict__ S) {
  int hh = threadIdx.x;
  int n0 = blockIdx.x * 32;
  float a0=0,a1=0,a2=0,a3=0,a4=0,a5=0,a6=0,a7=0;
  for (int i = 0; i < 32; ++i) {
    int node = n0 + i;
    int c = node_comm[node];
    float v = h[(size_t)node * 256 + hh];
    a0 += (c == 0) ? v : 0.f;  a1 += (c == 1) ? v : 0.f;
    a2 += (c == 2) ? v : 0.f;  a3 += (c == 3) ? v : 0.f;
    a4 += (c == 4) ? v : 0.f;  a5 += (c == 5) ? v : 0.f;
    a6 += (c == 6) ? v : 0.f;  a7 += (c == 7) ? v : 0.f;
  }
  if (a0 != 0.f) atomicAdd(&S[0 * 128 + hh], a0);
  if (a1 != 0.f) atomicAdd(&S[1 * 128 + hh], a1);
  if (a2 != 0.f) atomicAdd(&S[2 * 128 + hh], a2);
  if (a3 != 0.f) atomicAdd(&S[3 * 128 + hh], a3);
  if (a4 != 0.f) atomicAdd(&S[4 * 128 + hh], a4);
  if (a5 != 0.f) atomicAdd(&S[5 * 128 + hh], a5);
  if (a6 != 0.f) atomicAdd(&S[6 * 128 + hh], a6);
  if (a7 != 0.f) atomicAdd(&S[7 * 128 + hh], a7);
}

// ---------------- K3b: c = sigmoid(S/1024); cw = c @ Wb^T ----------------
__global__ __launch_bounds__(128) void k3b_cw(const float* __restrict__ S,
                                              const float* __restrict__ Wb,
                                              float* __restrict__ cw) {
  __shared__ float sc[128];
  int ci = blockIdx.x;                        // 0..7
  int hh = threadIdx.x;
  float m = S[ci * 128 + hh] * (1.0f / 1024.0f);
  sc[hh] = 1.0f / (1.0f + __expf(-m));
  __syncthreads();
  const float4* wr = (const float4*)(Wb + (size_t)hh * 128);
  float acc = 0.f;
#pragma unroll 8
  for (int k4 = 0; k4 < 32; ++k4) {
    float4 wv = wr[k4];
    acc += wv.x * sc[k4 * 4 + 0] + wv.y * sc[k4 * 4 + 1]
         + wv.z * sc[k4 * 4 + 2] + wv.w * sc[k4 * 4 + 3];
  }
  cw[ci * 128 + hh] = acc;
}

// ---------------- K5: per-node bilinear scores -> out ----------------
__global__ __launch_bounds__(256) void k5_score(const float* __restrict__ h,
                                                const int* __restrict__ node_comm,
                                                const float* __restrict__ cw,
                                                const float* __restrict__ bbp,
                                                float* __restrict__ out) {
  int tid = threadIdx.x;
  int q = tid & 15, nl = tid >> 4;
  int node = blockIdx.x * 16 + nl;
  int c = node_comm[node];
  const float* hr = h + (size_t)node * 256;
  const float* cr = cw + c * 128;
  float4 c0 = *(const float4*)(cr + q * 8);
  float4 c1 = *(const float4*)(cr + q * 8 + 4);
  float4 a0 = *(const float4*)(hr + q * 8);
  float4 a1 = *(const float4*)(hr + q * 8 + 4);
  float p1 = a0.x*c0.x + a0.y*c0.y + a0.z*c0.z + a0.w*c0.w
           + a1.x*c1.x + a1.y*c1.y + a1.z*c1.z + a1.w*c1.w;
  float4 b0 = *(const float4*)(hr + 128 + q * 8);
  float4 b1 = *(const float4*)(hr + 128 + q * 8 + 4);
  float p2 = b0.x*c0.x + b0.y*c0.y + b0.z*c0.z + b0.w*c0.w
           + b1.x*c1.x + b1.y*c1.y + b1.z*c1.z + b1.w*c1.w;
#pragma unroll
  for (int m = 8; m >= 1; m >>= 1) {
    p1 += __shfl_xor(p1, m, 64);
    p2 += __shfl_xor(p2, m, 64);
  }
  if (q == 0) {
    float bb = bbp[0];
    out[node] = p1 + bb;
    out[8192 + node] = p2 + bb;
  }
}

extern "C" void kernel_launch(void* const* d_in, const int* in_sizes, int n_in,
                              void* d_out, int out_size, void* d_ws, size_t ws_size,
                              hipStream_t stream) {
  (void)in_sizes; (void)n_in; (void)out_size; (void)ws_size;
  const float* seq1 = (const float*)d_in[0];
  const float* seq2 = (const float*)d_in[1];
  const float* adj  = (const float*)d_in[2];
  const int*   cc   = (const int*)d_in[3];
  const float* W    = (const float*)d_in[4];
  const float* b    = (const float*)d_in[5];
  const float* Wb   = (const float*)d_in[6];
  const float* bb   = (const float*)d_in[7];
  float* out = (float*)d_out;

  char* ws = (char*)d_ws;
  _Float16* F    = (_Float16*)(ws);                        // 4 MB
  float* h       = (float*)(ws + (4u << 20));              // 8 MB
  _Float16* Pp   = (_Float16*)(ws + (12u << 20));          // 16 MB
  float* S       = (float*)(ws + (44u << 20));             // 4 KB
  float* cw      = (float*)(ws + (44u << 20) + 4096);      // 4 KB
  int* node_comm = (int*)(ws + (44u << 20) + 8192);        // 32 KB

  k1_fts<<<dim3(128), dim3(256), 0, stream>>>(seq1, seq2, W, F, cc, node_comm, S);
  k2_gemm<<<dim3(256), dim3(512), 0, stream>>>(adj, F, Pp);
  k2r_reduce<<<dim3(2048), dim3(256), 0, stream>>>(Pp, b, h);
  k3a_csum<<<dim3(256), dim3(128), 0, stream>>>(h, node_comm, S);
  k3b_cw<<<dim3(8), dim3(128), 0, stream>>>(S, Wb, cw);
  k5_score<<<dim3(512), dim3(256), 0, stream>>>(h, node_comm, cw, bb, out);
}